// Round 4
// baseline (420.207 us; speedup 1.0000x reference)
//
#include <hip/hip_runtime.h>
#include <hip/hip_bf16.h>

typedef short bf16x8 __attribute__((ext_vector_type(8)));
typedef float f32x4 __attribute__((ext_vector_type(4)));
#define MFMA16 __builtin_amdgcn_mfma_f32_16x16x32_bf16

// ---- split-bf16 helpers -----------------------------------------------------
__device__ __forceinline__ unsigned short rne_bf16(float f) {
  unsigned u = __builtin_bit_cast(unsigned, f);
  return (unsigned short)((u + 0x7fffu + ((u >> 16) & 1u)) >> 16);
}
__device__ __forceinline__ float bf16f(unsigned short h) {
  unsigned u = ((unsigned)h) << 16;
  return __builtin_bit_cast(float, u);
}
__device__ __forceinline__ void split2(float f, short& h, short& l) {
  unsigned short hh = rne_bf16(f);
  h = (short)hh;
  l = (short)rne_bf16(f - bf16f(hh));
}

// ---- ws layout (short offsets) ----------------------------------------------
constexpr int NW_SH = 32768;   // node_W  256x128
constexpr int WC_SH = 16384;   // WcEt    128x128
constexpr int GF_SH = 65536;   // gfcn    128x512
constexpr int OFF_NWH = 0;
constexpr int OFF_NWL = NW_SH;
constexpr int OFF_WCH = 2 * NW_SH;
constexpr int OFF_WCL = 2 * NW_SH + WC_SH;
constexpr int OFF_GFH = 2 * NW_SH + 2 * WC_SH;
constexpr int OFF_GFL = 2 * NW_SH + 2 * WC_SH + GF_SH;
constexpr size_t OFF_BIAS_BYTES = (size_t)(2 * NW_SH + 2 * WC_SH + 2 * GF_SH) * 2;

// ---- setup: pack weights into MFMA fragment layout (hi/lo bf16 planes) ------
// packed[nf][kf][lane][j] = W[kf*32 + (lane>>4)*8 + j][nf*16 + (lane&15)]
__global__ __launch_bounds__(256) void setup_kernel(
    const float* __restrict__ node_W, const float* __restrict__ conv_W,
    const float* __restrict__ gfcn_W, const float* __restrict__ role_emb,
    const float* __restrict__ conv_b, const float* __restrict__ bn_gamma,
    const float* __restrict__ bn_beta, const float* __restrict__ bn_mean,
    const float* __restrict__ bn_var, short* __restrict__ wsS,
    float* __restrict__ bias_af) {
  int idx = blockIdx.x * 256 + threadIdx.x;
  int stride = gridDim.x * 256;
  for (int i = idx; i < 115456; i += stride) {
    if (i < 114688) {
      int j = i & 7, lane = (i >> 3) & 63;
      int kq = ((lane >> 4) & 3) * 8 + j, n16 = lane & 15;
      float val;
      short *ph, *pl;
      int loc;
      if (i < NW_SH) {
        loc = i;
        int f = i >> 9, kf = f & 7, nfr = f >> 3;
        int k = kf * 32 + kq, n = nfr * 16 + n16;
        val = node_W[k * 128 + n];
        ph = wsS + OFF_NWH; pl = wsS + OFF_NWL;
      } else if (i < NW_SH + WC_SH) {
        loc = i - NW_SH;
        int f = loc >> 9, kf = f & 3, nfr = f >> 2;
        int k = kf * 32 + kq, n = nfr * 16 + n16;
        float s = bn_gamma[n] * rsqrtf(bn_var[n] + 1e-5f);
        val = s * conv_W[n * 256 + 128 + k];     // WcEt[e=k][f=n]
        ph = wsS + OFF_WCH; pl = wsS + OFF_WCL;
      } else {
        loc = i - NW_SH - WC_SH;
        int f = loc >> 9, kf = f & 3, nfr = f >> 2;   // nfr 0..31
        int k = kf * 32 + kq, n = nfr * 16 + n16;     // n 0..511
        val = (n < 256) ? gfcn_W[k * 256 + n]
                        : gfcn_W[(128 + k) * 256 + (n - 256)];
        ph = wsS + OFF_GFH; pl = wsS + OFF_GFL;
      }
      short h, l;
      split2(val, h, l);
      ph[loc] = h; pl[loc] = l;
    } else {
      int loc = i - 114688;
      int a = loc >> 7, fc = loc & 127;
      int role = (a == 5) ? 6 : a;   // ROLES = {0,1,2,3,4,6}
      float s = bn_gamma[fc] * rsqrtf(bn_var[fc] + 1e-5f);
      float dot = 0.f;
      for (int e = 0; e < 128; ++e)
        dot = fmaf(role_emb[role * 128 + e], conv_W[fc * 256 + e], dot);
      bias_af[loc] = s * (dot + conv_b[fc] - bn_mean[fc]) + bn_beta[fc];
    }
  }
}

// ---- fused main kernel: 16 rows/block, 4 waves, 3 blocks/CU -----------------
__global__ __launch_bounds__(256, 3) void fused_kernel(
    const int* __restrict__ a_ids, const int* __restrict__ b_ids,
    const int* __restrict__ c_ids, const int* __restrict__ event_ids,
    const float* __restrict__ nf, const float* __restrict__ cond,
    const float* __restrict__ text, const float* __restrict__ ent,
    const float* __restrict__ node_b, const float* __restrict__ gfcn_b,
    const short* __restrict__ wsS, const float* __restrict__ bias_af,
    float* __restrict__ out) {
  __shared__ __align__(16) unsigned char smem[49152];
  short* lds_hi = (short*)smem;                 // 96x128 bf16 hi plane
  short* lds_lo = (short*)(smem + 24576);       // lo plane
  float* umin_s = (float*)smem;                 // overlay after planes dead
  float* vmin_s = (float*)(smem + 16640);       // stride 260 floats
  constexpr int OV = 260;

  const int t = threadIdx.x;
  const int wv = t >> 6, lane = t & 63;
  const int r15 = lane & 15, q = lane >> 4;
  const int b0 = blockIdx.x * 16;

  const bf16x8* nwh = (const bf16x8*)(wsS + OFF_NWH);
  const bf16x8* nwl = (const bf16x8*)(wsS + OFF_NWL);
  const bf16x8* wch = (const bf16x8*)(wsS + OFF_WCH);
  const bf16x8* wcl = (const bf16x8*)(wsS + OFF_WCL);
  const bf16x8* gfh = (const bf16x8*)(wsS + OFF_GFH);
  const bf16x8* gfl = (const bf16x8*)(wsS + OFF_GFL);

  // ---- ids direct (wave wv owns id-column wv; stack order a,event,b,c) ------
  const int* pw = (wv == 0) ? a_ids : (wv == 1) ? event_ids
                : (wv == 2) ? b_ids : c_ids;
  int my_id = pw[b0 + r15];
  int eid[4];
  #pragma unroll
  for (int rg = 0; rg < 4; ++rg) eid[rg] = pw[b0 + q * 4 + rg];
  const float* arow = nf + (size_t)my_id * 256 + q * 8;

  // ---- issue first-half gather loads (ks 0..3) ------------------------------
  float4 av[8];
  #pragma unroll
  for (int ks = 0; ks < 4; ++ks) {
    av[2 * ks]     = *(const float4*)(arow + ks * 32);
    av[2 * ks + 1] = *(const float4*)(arow + ks * 32 + 4);
  }

  // ---- cond_rel/text rows (a=4,5) -> planes (overlaps gather latency) -------
  #pragma unroll
  for (int j = 0; j < 16; ++j) {
    int i = j * 256 + t;
    int arr = i >> 11, rem = i & 2047, r = rem >> 7, e = rem & 127;
    const float* src = arr ? text : cond;
    float v = src[(size_t)(b0 + r) * 128 + e];
    short h, l;
    split2(v, h, l);
    int row = (4 + arr) * 16 + r;
    int si = row * 128 + (e ^ ((row & 7) << 3));
    lds_hi[si] = h; lds_lo[si] = l;
  }

  // ---- Stage B: vals[a] = entity + relu(nf@node_W + node_b), a = wave -------
  // ks-outer: acc[8] persistent (32 VGPR), A-frags live one half at a time.
  {
    f32x4 acc[8];
    #pragma unroll
    for (int n8 = 0; n8 < 8; ++n8) acc[n8] = (f32x4){0.f, 0.f, 0.f, 0.f};
    #pragma unroll
    for (int half = 0; half < 2; ++half) {
      bf16x8 ah[4], al[4];
      #pragma unroll
      for (int k4 = 0; k4 < 4; ++k4) {
        #pragma unroll
        for (int j = 0; j < 4; ++j) {
          short h, l;
          split2(av[2 * k4][j], h, l);
          ah[k4][j] = h; al[k4][j] = l;
          split2(av[2 * k4 + 1][j], h, l);
          ah[k4][4 + j] = h; al[k4][4 + j] = l;
        }
      }
      if (half == 0) {   // issue second-half gather loads under MFMA chain
        #pragma unroll
        for (int ks = 0; ks < 4; ++ks) {
          av[2 * ks]     = *(const float4*)(arow + (4 + ks) * 32);
          av[2 * ks + 1] = *(const float4*)(arow + (4 + ks) * 32 + 4);
        }
      }
      #pragma unroll
      for (int k4 = 0; k4 < 4; ++k4) {
        int ks = half * 4 + k4;
        #pragma unroll
        for (int n8 = 0; n8 < 8; ++n8) {
          bf16x8 bh = nwh[(n8 * 8 + ks) * 64 + lane];
          bf16x8 bl = nwl[(n8 * 8 + ks) * 64 + lane];
          acc[n8] = MFMA16(ah[k4], bh, acc[n8], 0, 0, 0);
          acc[n8] = MFMA16(al[k4], bh, acc[n8], 0, 0, 0);
          acc[n8] = MFMA16(ah[k4], bl, acc[n8], 0, 0, 0);
        }
      }
    }
    #pragma unroll
    for (int n8 = 0; n8 < 8; ++n8) {
      int col = n8 * 16 + r15;
      float nb = node_b[col];
      #pragma unroll
      for (int rg = 0; rg < 4; ++rg) {
        float e0 = ent[(size_t)eid[rg] * 128 + col];
        float v = e0 + fmaxf(acc[n8][rg] + nb, 0.f);
        short h, l; split2(v, h, l);
        int row = wv * 16 + q * 4 + rg;
        int si = row * 128 + (col ^ ((row & 7) << 3));
        lds_hi[si] = h; lds_lo[si] = l;
      }
    }
  }
  __syncthreads();

  // ---- Stage C: x = relu(vals @ WcEt + bias_af), wave owns 2 N-frags --------
  {
    f32x4 xacc[6][2];
    #pragma unroll
    for (int a = 0; a < 6; ++a) {
      xacc[a][0] = (f32x4){0.f, 0.f, 0.f, 0.f};
      xacc[a][1] = (f32x4){0.f, 0.f, 0.f, 0.f};
    }
    #pragma unroll
    for (int ks = 0; ks < 4; ++ks) {
      bf16x8 ah[6], al[6];
      int k0 = ks * 32 + q * 8;
      #pragma unroll
      for (int a = 0; a < 6; ++a) {
        int row = a * 16 + r15;
        int si = row * 128 + (k0 ^ ((row & 7) << 3));
        ah[a] = *(const bf16x8*)&lds_hi[si];
        al[a] = *(const bf16x8*)&lds_lo[si];
      }
      #pragma unroll
      for (int jn = 0; jn < 2; ++jn) {
        int nf4 = wv * 2 + jn;
        bf16x8 bh = wch[(nf4 * 4 + ks) * 64 + lane];
        bf16x8 bl = wcl[(nf4 * 4 + ks) * 64 + lane];
        #pragma unroll
        for (int a = 0; a < 6; ++a) {
          xacc[a][jn] = MFMA16(ah[a], bh, xacc[a][jn], 0, 0, 0);
          xacc[a][jn] = MFMA16(al[a], bh, xacc[a][jn], 0, 0, 0);
          xacc[a][jn] = MFMA16(ah[a], bl, xacc[a][jn], 0, 0, 0);
        }
      }
    }
    __syncthreads();   // all vals reads done
    #pragma unroll
    for (int a = 0; a < 6; ++a) {
      #pragma unroll
      for (int jn = 0; jn < 2; ++jn) {
        int col = (wv * 2 + jn) * 16 + r15;
        float bv = bias_af[a * 128 + col];
        #pragma unroll
        for (int rg = 0; rg < 4; ++rg) {
          float v = fmaxf(xacc[a][jn][rg] + bv, 0.f);
          short h, l; split2(v, h, l);
          int row = a * 16 + q * 4 + rg;
          int si = row * 128 + (col ^ ((row & 7) << 3));
          lds_hi[si] = h; lds_lo[si] = l;
        }
      }
    }
  }
  __syncthreads();

  // ---- Stage D: u/v = x @ gfcn, min over a; 4 groups of 2 N-frags (VGPR) ----
  f32x4 mreg[8];
  #pragma unroll
  for (int grp = 0; grp < 4; ++grp) {
    f32x4 acc[6][2];
    #pragma unroll
    for (int a = 0; a < 6; ++a) {
      acc[a][0] = (f32x4){0.f, 0.f, 0.f, 0.f};
      acc[a][1] = (f32x4){0.f, 0.f, 0.f, 0.f};
    }
    #pragma unroll
    for (int ks = 0; ks < 4; ++ks) {
      bf16x8 ah[6], al[6];
      int k0 = ks * 32 + q * 8;
      #pragma unroll
      for (int a = 0; a < 6; ++a) {
        int row = a * 16 + r15;
        int si = row * 128 + (k0 ^ ((row & 7) << 3));
        ah[a] = *(const bf16x8*)&lds_hi[si];
        al[a] = *(const bf16x8*)&lds_lo[si];
      }
      #pragma unroll
      for (int jn = 0; jn < 2; ++jn) {
        int nfg = wv * 8 + grp * 2 + jn;
        bf16x8 bh = gfh[(nfg * 4 + ks) * 64 + lane];
        bf16x8 bl = gfl[(nfg * 4 + ks) * 64 + lane];
        #pragma unroll
        for (int a = 0; a < 6; ++a) {
          acc[a][jn] = MFMA16(ah[a], bh, acc[a][jn], 0, 0, 0);
          acc[a][jn] = MFMA16(al[a], bh, acc[a][jn], 0, 0, 0);
          acc[a][jn] = MFMA16(ah[a], bl, acc[a][jn], 0, 0, 0);
        }
      }
    }
    #pragma unroll
    for (int jn = 0; jn < 2; ++jn) {
      #pragma unroll
      for (int rg = 0; rg < 4; ++rg) {
        float mm = acc[0][jn][rg];
        #pragma unroll
        for (int a = 1; a < 6; ++a) mm = fminf(mm, acc[a][jn][rg]);
        mreg[grp * 2 + jn][rg] = mm;
      }
    }
  }
  __syncthreads();   // all x reads done; planes now dead
  {
    float* dst = (wv >= 2) ? vmin_s : umin_s;
    int cbase = (wv & 1) * 128;
    #pragma unroll
    for (int j = 0; j < 8; ++j) {
      int colg = cbase + j * 16 + r15;
      #pragma unroll
      for (int rg = 0; rg < 4; ++rg)
        dst[(q * 4 + rg) * OV + colg] = mreg[j][rg];
    }
  }
  __syncthreads();
  #pragma unroll
  for (int j = 0; j < 16; ++j) {
    int i = j * 256 + t;
    int r = i >> 8, g = i & 255;
    out[(size_t)(b0 + r) * 256 + g] =
        fmaxf(umin_s[r * OV + g] + vmin_s[r * OV + g] + gfcn_b[g], 0.f);
  }
}

extern "C" void kernel_launch(void* const* d_in, const int* in_sizes, int n_in,
                              void* d_out, int out_size, void* d_ws, size_t ws_size,
                              hipStream_t stream) {
  const int* a_ids = (const int*)d_in[0];
  const int* b_ids = (const int*)d_in[1];
  const int* c_ids = (const int*)d_in[2];
  const int* event_ids = (const int*)d_in[3];
  const float* node_features = (const float*)d_in[4];
  const float* cond_rel = (const float*)d_in[5];
  const float* text = (const float*)d_in[6];
  const float* entity_emb = (const float*)d_in[7];
  const float* role_emb = (const float*)d_in[8];
  const float* node_W = (const float*)d_in[9];
  const float* node_b = (const float*)d_in[10];
  const float* conv_W = (const float*)d_in[11];
  const float* conv_b = (const float*)d_in[12];
  const float* bn_gamma = (const float*)d_in[13];
  const float* bn_beta = (const float*)d_in[14];
  const float* bn_mean = (const float*)d_in[15];
  const float* bn_var = (const float*)d_in[16];
  const float* gfcn_W = (const float*)d_in[17];
  const float* gfcn_b = (const float*)d_in[18];
  float* out = (float*)d_out;

  short* wsS = (short*)d_ws;
  float* bias_af = (float*)((char*)d_ws + OFF_BIAS_BYTES);
  const int B = in_sizes[0];   // 32768

  setup_kernel<<<452, 256, 0, stream>>>(node_W, conv_W, gfcn_W, role_emb,
                                        conv_b, bn_gamma, bn_beta, bn_mean,
                                        bn_var, wsS, bias_af);
  fused_kernel<<<B / 16, 256, 0, stream>>>(
      a_ids, b_ids, c_ids, event_ids, node_features, cond_rel, text,
      entity_emb, node_b, gfcn_b, wsS, bias_af, out);
}

// Round 5
// 360.497 us; speedup vs baseline: 1.1656x; 1.1656x over previous
//
#include <hip/hip_runtime.h>
#include <hip/hip_bf16.h>

typedef short bf16x8 __attribute__((ext_vector_type(8)));
typedef float f32x4 __attribute__((ext_vector_type(4)));
#define MFMA16 __builtin_amdgcn_mfma_f32_16x16x32_bf16

// ---- split-bf16 helpers -----------------------------------------------------
__device__ __forceinline__ unsigned short rne_bf16(float f) {
  unsigned u = __builtin_bit_cast(unsigned, f);
  return (unsigned short)((u + 0x7fffu + ((u >> 16) & 1u)) >> 16);
}
__device__ __forceinline__ float bf16f(unsigned short h) {
  unsigned u = ((unsigned)h) << 16;
  return __builtin_bit_cast(float, u);
}
__device__ __forceinline__ void split2(float f, short& h, short& l) {
  unsigned short hh = rne_bf16(f);
  h = (short)hh;
  l = (short)rne_bf16(f - bf16f(hh));
}

// ---- ws layout (short offsets) ----------------------------------------------
constexpr int NW_SH = 32768;   // node_W  256x128
constexpr int WC_SH = 16384;   // WcEt    128x128
constexpr int GF_SH = 65536;   // gfcn    128x512
constexpr int OFF_NWH = 0;
constexpr int OFF_NWL = NW_SH;
constexpr int OFF_WCH = 2 * NW_SH;
constexpr int OFF_WCL = 2 * NW_SH + WC_SH;
constexpr int OFF_GFH = 2 * NW_SH + 2 * WC_SH;
constexpr int OFF_GFL = 2 * NW_SH + 2 * WC_SH + GF_SH;
constexpr size_t OFF_BIAS_BYTES = (size_t)(2 * NW_SH + 2 * WC_SH + 2 * GF_SH) * 2;

// ---- setup: pack weights into MFMA fragment layout (hi/lo bf16 planes) ------
__global__ __launch_bounds__(256) void setup_kernel(
    const float* __restrict__ node_W, const float* __restrict__ conv_W,
    const float* __restrict__ gfcn_W, const float* __restrict__ role_emb,
    const float* __restrict__ conv_b, const float* __restrict__ bn_gamma,
    const float* __restrict__ bn_beta, const float* __restrict__ bn_mean,
    const float* __restrict__ bn_var, short* __restrict__ wsS,
    float* __restrict__ bias_af) {
  int idx = blockIdx.x * 256 + threadIdx.x;
  int stride = gridDim.x * 256;
  for (int i = idx; i < 115456; i += stride) {
    if (i < 114688) {
      int j = i & 7, lane = (i >> 3) & 63;
      int kq = ((lane >> 4) & 3) * 8 + j, n16 = lane & 15;
      float val;
      short *ph, *pl;
      int loc;
      if (i < NW_SH) {
        loc = i;
        int f = i >> 9, kf = f & 7, nfr = f >> 3;
        int k = kf * 32 + kq, n = nfr * 16 + n16;
        val = node_W[k * 128 + n];
        ph = wsS + OFF_NWH; pl = wsS + OFF_NWL;
      } else if (i < NW_SH + WC_SH) {
        loc = i - NW_SH;
        int f = loc >> 9, kf = f & 3, nfr = f >> 2;
        int k = kf * 32 + kq, n = nfr * 16 + n16;
        float s = bn_gamma[n] * rsqrtf(bn_var[n] + 1e-5f);
        val = s * conv_W[n * 256 + 128 + k];     // WcEt[e=k][f=n]
        ph = wsS + OFF_WCH; pl = wsS + OFF_WCL;
      } else {
        loc = i - NW_SH - WC_SH;
        int f = loc >> 9, kf = f & 3, nfr = f >> 2;   // nfr 0..31
        int k = kf * 32 + kq, n = nfr * 16 + n16;     // n 0..511
        val = (n < 256) ? gfcn_W[k * 256 + n]
                        : gfcn_W[(128 + k) * 256 + (n - 256)];
        ph = wsS + OFF_GFH; pl = wsS + OFF_GFL;
      }
      short h, l;
      split2(val, h, l);
      ph[loc] = h; pl[loc] = l;
    } else {
      int loc = i - 114688;
      int a = loc >> 7, fc = loc & 127;
      int role = (a == 5) ? 6 : a;   // ROLES = {0,1,2,3,4,6}
      float s = bn_gamma[fc] * rsqrtf(bn_var[fc] + 1e-5f);
      float dot = 0.f;
      for (int e = 0; e < 128; ++e)
        dot = fmaf(role_emb[role * 128 + e], conv_W[fc * 256 + e], dot);
      bias_af[loc] = s * (dot + conv_b[fc] - bn_mean[fc]) + bn_beta[fc];
    }
  }
}

// ---- fused main kernel: 16 rows/block, 4 waves, target 3 blocks/CU ----------
__global__ __launch_bounds__(256, 3) void fused_kernel(
    const int* __restrict__ a_ids, const int* __restrict__ b_ids,
    const int* __restrict__ c_ids, const int* __restrict__ event_ids,
    const float* __restrict__ nf, const float* __restrict__ cond,
    const float* __restrict__ text, const float* __restrict__ ent,
    const float* __restrict__ node_b, const float* __restrict__ gfcn_b,
    const short* __restrict__ wsS, const float* __restrict__ bias_af,
    float* __restrict__ out) {
  __shared__ __align__(16) unsigned char smem[49152];
  short* lds_hi = (short*)smem;                 // 96x128 bf16 hi plane
  short* lds_lo = (short*)(smem + 24576);       // lo plane
  float* umin_s = (float*)smem;                 // overlay after planes dead
  float* vmin_s = (float*)(smem + 16640);       // stride 260 floats
  constexpr int OV = 260;

  const int t = threadIdx.x;
  const int wv = t >> 6, lane = t & 63;
  const int r15 = lane & 15, q = lane >> 4;
  const int b0 = blockIdx.x * 16;

  const bf16x8* nwh = (const bf16x8*)(wsS + OFF_NWH);
  const bf16x8* nwl = (const bf16x8*)(wsS + OFF_NWL);
  const bf16x8* wch = (const bf16x8*)(wsS + OFF_WCH);
  const bf16x8* wcl = (const bf16x8*)(wsS + OFF_WCL);
  const bf16x8* gfh = (const bf16x8*)(wsS + OFF_GFH);
  const bf16x8* gfl = (const bf16x8*)(wsS + OFF_GFL);

  // ---- ids direct (wave wv owns id-column wv; stack order a,event,b,c) ------
  const int* pw = (wv == 0) ? a_ids : (wv == 1) ? event_ids
                : (wv == 2) ? b_ids : c_ids;
  int my_id = pw[b0 + r15];
  int eid[4];
  #pragma unroll
  for (int rg = 0; rg < 4; ++rg) eid[rg] = pw[b0 + q * 4 + rg];
  const float* arow = nf + (size_t)my_id * 256 + q * 8;

  // ---- first-half gather loads (ks 0..3); latency hides under staging -------
  float4 avA[8];
  #pragma unroll
  for (int ks = 0; ks < 4; ++ks) {
    avA[2 * ks]     = *(const float4*)(arow + ks * 32);
    avA[2 * ks + 1] = *(const float4*)(arow + ks * 32 + 4);
  }

  // ---- cond_rel/text rows (a=4,5) -> planes ----
  #pragma unroll
  for (int j = 0; j < 16; ++j) {
    int i = j * 256 + t;
    int arr = i >> 11, rem = i & 2047, r = rem >> 7, e = rem & 127;
    const float* src = arr ? text : cond;
    float v = src[(size_t)(b0 + r) * 128 + e];
    short h, l;
    split2(v, h, l);
    int row = (4 + arr) * 16 + r;
    int si = row * 128 + (e ^ ((row & 7) << 3));
    lds_hi[si] = h; lds_lo[si] = l;
  }

  // ---- Stage B: vals[a] = entity + relu(nf@node_W + node_b), a = wave -------
  // ks-outer, n8-inner: acc[8] = 8 independent MFMA chains; A-frags transient.
  {
    f32x4 acc[8];
    #pragma unroll
    for (int n8 = 0; n8 < 8; ++n8) acc[n8] = (f32x4){0.f, 0.f, 0.f, 0.f};
    float4 avB[8];
    #pragma unroll
    for (int ks = 0; ks < 4; ++ks) {   // second-half loads; hide under MFMA
      avB[2 * ks]     = *(const float4*)(arow + (4 + ks) * 32);
      avB[2 * ks + 1] = *(const float4*)(arow + (4 + ks) * 32 + 4);
    }
    #pragma unroll
    for (int ks = 0; ks < 8; ++ks) {
      bf16x8 ah, al;
      {
        float4 v0 = (ks < 4) ? avA[2 * ks] : avB[2 * (ks - 4)];
        float4 v1 = (ks < 4) ? avA[2 * ks + 1] : avB[2 * (ks - 4) + 1];
        #pragma unroll
        for (int j = 0; j < 4; ++j) {
          short h, l;
          split2(v0[j], h, l);
          ah[j] = h; al[j] = l;
          split2(v1[j], h, l);
          ah[4 + j] = h; al[4 + j] = l;
        }
      }
      #pragma unroll
      for (int n8 = 0; n8 < 8; ++n8) {
        bf16x8 bh = nwh[(n8 * 8 + ks) * 64 + lane];
        bf16x8 bl = nwl[(n8 * 8 + ks) * 64 + lane];
        acc[n8] = MFMA16(ah, bh, acc[n8], 0, 0, 0);
        acc[n8] = MFMA16(al, bh, acc[n8], 0, 0, 0);
        acc[n8] = MFMA16(ah, bl, acc[n8], 0, 0, 0);
      }
    }
    // hoisted ent gather (one latency batch)
    float ev[32];
    #pragma unroll
    for (int n8 = 0; n8 < 8; ++n8)
      #pragma unroll
      for (int rg = 0; rg < 4; ++rg)
        ev[n8 * 4 + rg] = ent[(size_t)eid[rg] * 128 + n8 * 16 + r15];
    #pragma unroll
    for (int n8 = 0; n8 < 8; ++n8) {
      int col = n8 * 16 + r15;
      float nb = node_b[col];
      #pragma unroll
      for (int rg = 0; rg < 4; ++rg) {
        float v = ev[n8 * 4 + rg] + fmaxf(acc[n8][rg] + nb, 0.f);
        short h, l; split2(v, h, l);
        int row = wv * 16 + q * 4 + rg;
        int si = row * 128 + (col ^ ((row & 7) << 3));
        lds_hi[si] = h; lds_lo[si] = l;
      }
    }
  }
  __syncthreads();

  // ---- Stage C: x = relu(vals @ WcEt + bias_af); A-frags 3 a's at a time ----
  {
    f32x4 xacc[6][2];
    #pragma unroll
    for (int a = 0; a < 6; ++a) {
      xacc[a][0] = (f32x4){0.f, 0.f, 0.f, 0.f};
      xacc[a][1] = (f32x4){0.f, 0.f, 0.f, 0.f};
    }
    #pragma unroll
    for (int ks = 0; ks < 4; ++ks) {
      int k0 = ks * 32 + q * 8;
      #pragma unroll
      for (int ha = 0; ha < 2; ++ha) {
        bf16x8 ah[3], al[3];
        #pragma unroll
        for (int j = 0; j < 3; ++j) {
          int row = (ha * 3 + j) * 16 + r15;
          int si = row * 128 + (k0 ^ ((row & 7) << 3));
          ah[j] = *(const bf16x8*)&lds_hi[si];
          al[j] = *(const bf16x8*)&lds_lo[si];
        }
        #pragma unroll
        for (int jn = 0; jn < 2; ++jn) {
          bf16x8 bh = wch[((wv * 2 + jn) * 4 + ks) * 64 + lane];
          bf16x8 bl = wcl[((wv * 2 + jn) * 4 + ks) * 64 + lane];
          #pragma unroll
          for (int j = 0; j < 3; ++j) {
            int a = ha * 3 + j;
            xacc[a][jn] = MFMA16(ah[j], bh, xacc[a][jn], 0, 0, 0);
            xacc[a][jn] = MFMA16(al[j], bh, xacc[a][jn], 0, 0, 0);
            xacc[a][jn] = MFMA16(ah[j], bl, xacc[a][jn], 0, 0, 0);
          }
        }
      }
    }
    __syncthreads();   // all vals reads done
    #pragma unroll
    for (int a = 0; a < 6; ++a) {
      #pragma unroll
      for (int jn = 0; jn < 2; ++jn) {
        int col = (wv * 2 + jn) * 16 + r15;
        float bv = bias_af[a * 128 + col];
        #pragma unroll
        for (int rg = 0; rg < 4; ++rg) {
          float v = fmaxf(xacc[a][jn][rg] + bv, 0.f);
          short h, l; split2(v, h, l);
          int row = a * 16 + q * 4 + rg;
          int si = row * 128 + (col ^ ((row & 7) << 3));
          lds_hi[si] = h; lds_lo[si] = l;
        }
      }
    }
  }
  __syncthreads();

  // ---- Stage D: u/v = x @ gfcn, min over a; 4 grps x 2 jn; 3-a A-batches ----
  f32x4 mreg[8];
  #pragma unroll
  for (int grp = 0; grp < 4; ++grp) {
    f32x4 acc[6][2];
    #pragma unroll
    for (int a = 0; a < 6; ++a) {
      acc[a][0] = (f32x4){0.f, 0.f, 0.f, 0.f};
      acc[a][1] = (f32x4){0.f, 0.f, 0.f, 0.f};
    }
    #pragma unroll
    for (int ks = 0; ks < 4; ++ks) {
      int k0 = ks * 32 + q * 8;
      #pragma unroll
      for (int ha = 0; ha < 2; ++ha) {
        bf16x8 ah[3], al[3];
        #pragma unroll
        for (int j = 0; j < 3; ++j) {
          int row = (ha * 3 + j) * 16 + r15;
          int si = row * 128 + (k0 ^ ((row & 7) << 3));
          ah[j] = *(const bf16x8*)&lds_hi[si];
          al[j] = *(const bf16x8*)&lds_lo[si];
        }
        #pragma unroll
        for (int jn = 0; jn < 2; ++jn) {
          int nfg = wv * 8 + grp * 2 + jn;
          bf16x8 bh = gfh[(nfg * 4 + ks) * 64 + lane];
          bf16x8 bl = gfl[(nfg * 4 + ks) * 64 + lane];
          #pragma unroll
          for (int j = 0; j < 3; ++j) {
            int a = ha * 3 + j;
            acc[a][jn] = MFMA16(ah[j], bh, acc[a][jn], 0, 0, 0);
            acc[a][jn] = MFMA16(al[j], bh, acc[a][jn], 0, 0, 0);
            acc[a][jn] = MFMA16(ah[j], bl, acc[a][jn], 0, 0, 0);
          }
        }
      }
    }
    #pragma unroll
    for (int jn = 0; jn < 2; ++jn) {
      #pragma unroll
      for (int rg = 0; rg < 4; ++rg) {
        float mm = acc[0][jn][rg];
        #pragma unroll
        for (int a = 1; a < 6; ++a) mm = fminf(mm, acc[a][jn][rg]);
        mreg[grp * 2 + jn][rg] = mm;
      }
    }
  }
  __syncthreads();   // all x reads done; planes now dead
  {
    float* dst = (wv >= 2) ? vmin_s : umin_s;
    int cbase = (wv & 1) * 128;
    #pragma unroll
    for (int j = 0; j < 8; ++j) {
      int colg = cbase + j * 16 + r15;
      #pragma unroll
      for (int rg = 0; rg < 4; ++rg)
        dst[(q * 4 + rg) * OV + colg] = mreg[j][rg];
    }
  }
  __syncthreads();
  #pragma unroll
  for (int j = 0; j < 16; ++j) {
    int i = j * 256 + t;
    int r = i >> 8, g = i & 255;
    out[(size_t)(b0 + r) * 256 + g] =
        fmaxf(umin_s[r * OV + g] + vmin_s[r * OV + g] + gfcn_b[g], 0.f);
  }
}

extern "C" void kernel_launch(void* const* d_in, const int* in_sizes, int n_in,
                              void* d_out, int out_size, void* d_ws, size_t ws_size,
                              hipStream_t stream) {
  const int* a_ids = (const int*)d_in[0];
  const int* b_ids = (const int*)d_in[1];
  const int* c_ids = (const int*)d_in[2];
  const int* event_ids = (const int*)d_in[3];
  const float* node_features = (const float*)d_in[4];
  const float* cond_rel = (const float*)d_in[5];
  const float* text = (const float*)d_in[6];
  const float* entity_emb = (const float*)d_in[7];
  const float* role_emb = (const float*)d_in[8];
  const float* node_W = (const float*)d_in[9];
  const float* node_b = (const float*)d_in[10];
  const float* conv_W = (const float*)d_in[11];
  const float* conv_b = (const float*)d_in[12];
  const float* bn_gamma = (const float*)d_in[13];
  const float* bn_beta = (const float*)d_in[14];
  const float* bn_mean = (const float*)d_in[15];
  const float* bn_var = (const float*)d_in[16];
  const float* gfcn_W = (const float*)d_in[17];
  const float* gfcn_b = (const float*)d_in[18];
  float* out = (float*)d_out;

  short* wsS = (short*)d_ws;
  float* bias_af = (float*)((char*)d_ws + OFF_BIAS_BYTES);
  const int B = in_sizes[0];   // 32768

  setup_kernel<<<452, 256, 0, stream>>>(node_W, conv_W, gfcn_W, role_emb,
                                        conv_b, bn_gamma, bn_beta, bn_mean,
                                        bn_var, wsS, bias_af);
  fused_kernel<<<B / 16, 256, 0, stream>>>(
      a_ids, b_ids, c_ids, event_ids, node_features, cond_rel, text,
      entity_emb, node_b, gfcn_b, wsS, bias_af, out);
}

// Round 6
// 244.282 us; speedup vs baseline: 1.7202x; 1.4757x over previous
//
#include <hip/hip_runtime.h>
#include <hip/hip_bf16.h>

typedef short bf16x8 __attribute__((ext_vector_type(8)));
typedef float f32x4 __attribute__((ext_vector_type(4)));
#define MFMA16 __builtin_amdgcn_mfma_f32_16x16x32_bf16

// ---- split-bf16 helpers -----------------------------------------------------
__device__ __forceinline__ unsigned short rne_bf16(float f) {
  unsigned u = __builtin_bit_cast(unsigned, f);
  return (unsigned short)((u + 0x7fffu + ((u >> 16) & 1u)) >> 16);
}
__device__ __forceinline__ float bf16f(unsigned short h) {
  unsigned u = ((unsigned)h) << 16;
  return __builtin_bit_cast(float, u);
}
__device__ __forceinline__ void split2(float f, short& h, short& l) {
  unsigned short hh = rne_bf16(f);
  h = (short)hh;
  l = (short)rne_bf16(f - bf16f(hh));
}

// ---- ws layout --------------------------------------------------------------
constexpr int NW_SH = 32768;   // node_W  256x128
constexpr int WC_SH = 16384;   // WcEt    128x128
constexpr int GF_SH = 65536;   // gfcn    128x512
constexpr int OFF_NWH = 0;
constexpr int OFF_NWL = NW_SH;
constexpr int OFF_WCH = 2 * NW_SH;
constexpr int OFF_WCL = 2 * NW_SH + WC_SH;
constexpr int OFF_GFH = 2 * NW_SH + 2 * WC_SH;
constexpr int OFF_GFL = 2 * NW_SH + 2 * WC_SH + GF_SH;
constexpr size_t OFF_BIAS_BYTES = (size_t)(2 * NW_SH + 2 * WC_SH + 2 * GF_SH) * 2; // 458752
constexpr size_t OFF_VF_BYTES = OFF_BIAS_BYTES + 6 * 128 * 4;                      // 461824
constexpr int NT_MAX = 2048;                    // B/16
constexpr int VF_SH = NT_MAX * 4 * 4 * 64 * 8;  // 16777216 shorts per plane
constexpr size_t WS_NEED = OFF_VF_BYTES + (size_t)2 * (size_t)VF_SH * 2;           // ~67.6 MB

// ---- setup: pack weights into MFMA fragment layout (hi/lo bf16 planes) ------
__global__ __launch_bounds__(256) void setup_kernel(
    const float* __restrict__ node_W, const float* __restrict__ conv_W,
    const float* __restrict__ gfcn_W, const float* __restrict__ role_emb,
    const float* __restrict__ conv_b, const float* __restrict__ bn_gamma,
    const float* __restrict__ bn_beta, const float* __restrict__ bn_mean,
    const float* __restrict__ bn_var, short* __restrict__ wsS,
    float* __restrict__ bias_af) {
  int idx = blockIdx.x * 256 + threadIdx.x;
  int stride = gridDim.x * 256;
  for (int i = idx; i < 115456; i += stride) {
    if (i < 114688) {
      int j = i & 7, lane = (i >> 3) & 63;
      int kq = ((lane >> 4) & 3) * 8 + j, n16 = lane & 15;
      float val;
      short *ph, *pl;
      int loc;
      if (i < NW_SH) {
        loc = i;
        int f = i >> 9, kf = f & 7, nfr = f >> 3;
        int k = kf * 32 + kq, n = nfr * 16 + n16;
        val = node_W[k * 128 + n];
        ph = wsS + OFF_NWH; pl = wsS + OFF_NWL;
      } else if (i < NW_SH + WC_SH) {
        loc = i - NW_SH;
        int f = loc >> 9, kf = f & 3, nfr = f >> 2;
        int k = kf * 32 + kq, n = nfr * 16 + n16;
        float s = bn_gamma[n] * rsqrtf(bn_var[n] + 1e-5f);
        val = s * conv_W[n * 256 + 128 + k];     // WcEt[e=k][f=n]
        ph = wsS + OFF_WCH; pl = wsS + OFF_WCL;
      } else {
        loc = i - NW_SH - WC_SH;
        int f = loc >> 9, kf = f & 3, nfr = f >> 2;   // nfr 0..31
        int k = kf * 32 + kq, n = nfr * 16 + n16;     // n 0..511
        val = (n < 256) ? gfcn_W[k * 256 + n]
                        : gfcn_W[(128 + k) * 256 + (n - 256)];
        ph = wsS + OFF_GFH; pl = wsS + OFF_GFL;
      }
      short h, l;
      split2(val, h, l);
      ph[loc] = h; pl[loc] = l;
    } else {
      int loc = i - 114688;
      int a = loc >> 7, fc = loc & 127;
      int role = (a == 5) ? 6 : a;   // ROLES = {0,1,2,3,4,6}
      float s = bn_gamma[fc] * rsqrtf(bn_var[fc] + 1e-5f);
      float dot = 0.f;
      for (int e = 0; e < 128; ++e)
        dot = fmaf(role_emb[role * 128 + e], conv_W[fc * 256 + e], dot);
      bias_af[loc] = s * (dot + conv_b[fc] - bn_mean[fc]) + bn_beta[fc];
    }
  }
}

// ---- kernel A: vals[a] = entity + relu(nf@node_W + node_b) -> ws A-frags ----
__global__ __launch_bounds__(256) void ent_kernel(
    const int* __restrict__ a_ids, const int* __restrict__ b_ids,
    const int* __restrict__ c_ids, const int* __restrict__ event_ids,
    const float* __restrict__ nf, const float* __restrict__ ent,
    const float* __restrict__ node_b, const short* __restrict__ wsS,
    short* __restrict__ vfh, short* __restrict__ vfl) {
  __shared__ __align__(16) short lhs[64 * 128];
  __shared__ __align__(16) short lls[64 * 128];
  const int t = threadIdx.x;
  const int wv = t >> 6, lane = t & 63;
  const int r15 = lane & 15, q = lane >> 4;
  const int tile = blockIdx.x;
  const int b0 = tile * 16;

  const bf16x8* nwh = (const bf16x8*)(wsS + OFF_NWH);
  const bf16x8* nwl = (const bf16x8*)(wsS + OFF_NWL);

  // wave wv owns id-column wv; stack order a,event,b,c
  const int* pw = (wv == 0) ? a_ids : (wv == 1) ? event_ids
                : (wv == 2) ? b_ids : c_ids;
  int my_id = pw[b0 + r15];
  int eid[4];
  #pragma unroll
  for (int rg = 0; rg < 4; ++rg) eid[rg] = pw[b0 + q * 4 + rg];
  const float* arow = nf + (size_t)my_id * 256 + q * 8;

  float4 avA[8];
  #pragma unroll
  for (int ks = 0; ks < 4; ++ks) {
    avA[2 * ks]     = *(const float4*)(arow + ks * 32);
    avA[2 * ks + 1] = *(const float4*)(arow + ks * 32 + 4);
  }

  f32x4 acc[8];
  #pragma unroll
  for (int n8 = 0; n8 < 8; ++n8) acc[n8] = (f32x4){0.f, 0.f, 0.f, 0.f};
  float4 avB[8];
  #pragma unroll
  for (int ks = 0; ks < 4; ++ks) {
    avB[2 * ks]     = *(const float4*)(arow + (4 + ks) * 32);
    avB[2 * ks + 1] = *(const float4*)(arow + (4 + ks) * 32 + 4);
  }
  #pragma unroll
  for (int ks = 0; ks < 8; ++ks) {
    bf16x8 ah, al;
    {
      float4 v0 = (ks < 4) ? avA[2 * ks] : avB[2 * (ks - 4)];
      float4 v1 = (ks < 4) ? avA[2 * ks + 1] : avB[2 * (ks - 4) + 1];
      #pragma unroll
      for (int j = 0; j < 4; ++j) {
        short h, l;
        split2(v0[j], h, l);
        ah[j] = h; al[j] = l;
        split2(v1[j], h, l);
        ah[4 + j] = h; al[4 + j] = l;
      }
    }
    #pragma unroll
    for (int n8 = 0; n8 < 8; ++n8) {
      bf16x8 bh = nwh[(n8 * 8 + ks) * 64 + lane];
      bf16x8 bl = nwl[(n8 * 8 + ks) * 64 + lane];
      acc[n8] = MFMA16(ah, bh, acc[n8], 0, 0, 0);
      acc[n8] = MFMA16(al, bh, acc[n8], 0, 0, 0);
      acc[n8] = MFMA16(ah, bl, acc[n8], 0, 0, 0);
    }
  }
  // hoisted ent gather
  float ev[32];
  #pragma unroll
  for (int n8 = 0; n8 < 8; ++n8)
    #pragma unroll
    for (int rg = 0; rg < 4; ++rg)
      ev[n8 * 4 + rg] = ent[(size_t)eid[rg] * 128 + n8 * 16 + r15];
  #pragma unroll
  for (int n8 = 0; n8 < 8; ++n8) {
    int col = n8 * 16 + r15;
    float nb = node_b[col];
    #pragma unroll
    for (int rg = 0; rg < 4; ++rg) {
      float v = ev[n8 * 4 + rg] + fmaxf(acc[n8][rg] + nb, 0.f);
      short h, l; split2(v, h, l);
      int row = wv * 16 + q * 4 + rg;
      int si = row * 128 + (col ^ ((row & 7) << 3));
      lhs[si] = h; lls[si] = l;
    }
  }
  __syncthreads();
  // frag-layout read, coalesced ws store
  #pragma unroll
  for (int ks = 0; ks < 4; ++ks) {
    int row = wv * 16 + r15;
    int k0 = ks * 32 + q * 8;
    int si = row * 128 + (k0 ^ ((row & 7) << 3));
    ((bf16x8*)vfh)[((tile * 4 + wv) * 4 + ks) * 64 + lane] = *(const bf16x8*)&lhs[si];
    ((bf16x8*)vfl)[((tile * 4 + wv) * 4 + ks) * 64 + lane] = *(const bf16x8*)&lls[si];
  }
}

// ---- kernel B: stages C+D ---------------------------------------------------
__global__ __launch_bounds__(256) void head_kernel(
    const float* __restrict__ cond, const float* __restrict__ text,
    const float* __restrict__ gfcn_b, const short* __restrict__ wsS,
    const float* __restrict__ bias_af, const short* __restrict__ vfh,
    const short* __restrict__ vfl, float* __restrict__ out) {
  __shared__ __align__(16) unsigned char smem[49152];
  short* lds_hi = (short*)smem;                 // 96x128 bf16 hi plane (x)
  short* lds_lo = (short*)(smem + 24576);       // lo plane
  float* umin_s = (float*)smem;                 // overlay after planes dead
  float* vmin_s = (float*)(smem + 16640);       // stride 260 floats
  constexpr int OV = 260;

  const int t = threadIdx.x;
  const int wv = t >> 6, lane = t & 63;
  const int r15 = lane & 15, q = lane >> 4;
  const int tile = blockIdx.x;
  const int b0 = tile * 16;

  const bf16x8* wch = (const bf16x8*)(wsS + OFF_WCH);
  const bf16x8* wcl = (const bf16x8*)(wsS + OFF_WCL);
  const bf16x8* gfh = (const bf16x8*)(wsS + OFF_GFH);
  const bf16x8* gfl = (const bf16x8*)(wsS + OFF_GFL);
  const bf16x8* vfh8 = (const bf16x8*)vfh;
  const bf16x8* vfl8 = (const bf16x8*)vfl;

  // ---- Stage C: x = relu(vals @ WcEt + bias_af); A-frags from ws/global -----
  {
    f32x4 xacc[6][2];
    #pragma unroll
    for (int a = 0; a < 6; ++a) {
      xacc[a][0] = (f32x4){0.f, 0.f, 0.f, 0.f};
      xacc[a][1] = (f32x4){0.f, 0.f, 0.f, 0.f};
    }
    #pragma unroll
    for (int ks = 0; ks < 4; ++ks) {
      int k0 = ks * 32 + q * 8;
      #pragma unroll
      for (int ha = 0; ha < 2; ++ha) {
        bf16x8 ah[3], al[3];
        #pragma unroll
        for (int j = 0; j < 3; ++j) {
          int a = ha * 3 + j;
          if (a < 4) {
            ah[j] = vfh8[((tile * 4 + a) * 4 + ks) * 64 + lane];
            al[j] = vfl8[((tile * 4 + a) * 4 + ks) * 64 + lane];
          } else {
            const float* src = (a == 4) ? cond : text;
            const float* p = src + (size_t)(b0 + r15) * 128 + k0;
            float4 v0 = *(const float4*)p;
            float4 v1 = *(const float4*)(p + 4);
            #pragma unroll
            for (int jj = 0; jj < 4; ++jj) {
              short h, l;
              split2(v0[jj], h, l);
              ah[j][jj] = h; al[j][jj] = l;
              split2(v1[jj], h, l);
              ah[j][4 + jj] = h; al[j][4 + jj] = l;
            }
          }
        }
        #pragma unroll
        for (int jn = 0; jn < 2; ++jn) {
          bf16x8 bh = wch[((wv * 2 + jn) * 4 + ks) * 64 + lane];
          bf16x8 bl = wcl[((wv * 2 + jn) * 4 + ks) * 64 + lane];
          #pragma unroll
          for (int j = 0; j < 3; ++j) {
            int a = ha * 3 + j;
            xacc[a][jn] = MFMA16(ah[j], bh, xacc[a][jn], 0, 0, 0);
            xacc[a][jn] = MFMA16(al[j], bh, xacc[a][jn], 0, 0, 0);
            xacc[a][jn] = MFMA16(ah[j], bl, xacc[a][jn], 0, 0, 0);
          }
        }
      }
    }
    // epilogue: x -> LDS planes (first LDS writes; no barrier needed before)
    #pragma unroll
    for (int a = 0; a < 6; ++a) {
      #pragma unroll
      for (int jn = 0; jn < 2; ++jn) {
        int col = (wv * 2 + jn) * 16 + r15;
        float bv = bias_af[a * 128 + col];
        #pragma unroll
        for (int rg = 0; rg < 4; ++rg) {
          float v = fmaxf(xacc[a][jn][rg] + bv, 0.f);
          short h, l; split2(v, h, l);
          int row = a * 16 + q * 4 + rg;
          int si = row * 128 + (col ^ ((row & 7) << 3));
          lds_hi[si] = h; lds_lo[si] = l;
        }
      }
    }
  }
  __syncthreads();

  // ---- Stage D: u/v = x @ gfcn, min over a; 4 grps x 2 jn; 3-a A-batches ----
  f32x4 mreg[8];
  #pragma unroll
  for (int grp = 0; grp < 4; ++grp) {
    f32x4 acc[6][2];
    #pragma unroll
    for (int a = 0; a < 6; ++a) {
      acc[a][0] = (f32x4){0.f, 0.f, 0.f, 0.f};
      acc[a][1] = (f32x4){0.f, 0.f, 0.f, 0.f};
    }
    #pragma unroll
    for (int ks = 0; ks < 4; ++ks) {
      int k0 = ks * 32 + q * 8;
      #pragma unroll
      for (int ha = 0; ha < 2; ++ha) {
        bf16x8 ah[3], al[3];
        #pragma unroll
        for (int j = 0; j < 3; ++j) {
          int row = (ha * 3 + j) * 16 + r15;
          int si = row * 128 + (k0 ^ ((row & 7) << 3));
          ah[j] = *(const bf16x8*)&lds_hi[si];
          al[j] = *(const bf16x8*)&lds_lo[si];
        }
        #pragma unroll
        for (int jn = 0; jn < 2; ++jn) {
          int nfg = wv * 8 + grp * 2 + jn;
          bf16x8 bh = gfh[(nfg * 4 + ks) * 64 + lane];
          bf16x8 bl = gfl[(nfg * 4 + ks) * 64 + lane];
          #pragma unroll
          for (int j = 0; j < 3; ++j) {
            int a = ha * 3 + j;
            acc[a][jn] = MFMA16(ah[j], bh, acc[a][jn], 0, 0, 0);
            acc[a][jn] = MFMA16(al[j], bh, acc[a][jn], 0, 0, 0);
            acc[a][jn] = MFMA16(ah[j], bl, acc[a][jn], 0, 0, 0);
          }
        }
      }
    }
    #pragma unroll
    for (int jn = 0; jn < 2; ++jn) {
      #pragma unroll
      for (int rg = 0; rg < 4; ++rg) {
        float mm = acc[0][jn][rg];
        #pragma unroll
        for (int a = 1; a < 6; ++a) mm = fminf(mm, acc[a][jn][rg]);
        mreg[grp * 2 + jn][rg] = mm;
      }
    }
  }
  __syncthreads();   // all x reads done; planes now dead
  {
    float* dst = (wv >= 2) ? vmin_s : umin_s;
    int cbase = (wv & 1) * 128;
    #pragma unroll
    for (int j = 0; j < 8; ++j) {
      int colg = cbase + j * 16 + r15;
      #pragma unroll
      for (int rg = 0; rg < 4; ++rg)
        dst[(q * 4 + rg) * OV + colg] = mreg[j][rg];
    }
  }
  __syncthreads();
  #pragma unroll
  for (int j = 0; j < 16; ++j) {
    int i = j * 256 + t;
    int r = i >> 8, g = i & 255;
    out[(size_t)(b0 + r) * 256 + g] =
        fmaxf(umin_s[r * OV + g] + vmin_s[r * OV + g] + gfcn_b[g], 0.f);
  }
}

// ---- fallback: fused (R5 structure, no min-wave bound) ----------------------
__global__ __launch_bounds__(256) void fused_fallback(
    const int* __restrict__ a_ids, const int* __restrict__ b_ids,
    const int* __restrict__ c_ids, const int* __restrict__ event_ids,
    const float* __restrict__ nf, const float* __restrict__ cond,
    const float* __restrict__ text, const float* __restrict__ ent,
    const float* __restrict__ node_b, const float* __restrict__ gfcn_b,
    const short* __restrict__ wsS, const float* __restrict__ bias_af,
    float* __restrict__ out) {
  __shared__ __align__(16) unsigned char smem[49152];
  short* lds_hi = (short*)smem;
  short* lds_lo = (short*)(smem + 24576);
  float* umin_s = (float*)smem;
  float* vmin_s = (float*)(smem + 16640);
  constexpr int OV = 260;

  const int t = threadIdx.x;
  const int wv = t >> 6, lane = t & 63;
  const int r15 = lane & 15, q = lane >> 4;
  const int b0 = blockIdx.x * 16;

  const bf16x8* nwh = (const bf16x8*)(wsS + OFF_NWH);
  const bf16x8* nwl = (const bf16x8*)(wsS + OFF_NWL);
  const bf16x8* wch = (const bf16x8*)(wsS + OFF_WCH);
  const bf16x8* wcl = (const bf16x8*)(wsS + OFF_WCL);
  const bf16x8* gfh = (const bf16x8*)(wsS + OFF_GFH);
  const bf16x8* gfl = (const bf16x8*)(wsS + OFF_GFL);

  const int* pw = (wv == 0) ? a_ids : (wv == 1) ? event_ids
                : (wv == 2) ? b_ids : c_ids;
  int my_id = pw[b0 + r15];
  int eid[4];
  #pragma unroll
  for (int rg = 0; rg < 4; ++rg) eid[rg] = pw[b0 + q * 4 + rg];
  const float* arow = nf + (size_t)my_id * 256 + q * 8;

  float4 avA[8];
  #pragma unroll
  for (int ks = 0; ks < 4; ++ks) {
    avA[2 * ks]     = *(const float4*)(arow + ks * 32);
    avA[2 * ks + 1] = *(const float4*)(arow + ks * 32 + 4);
  }
  #pragma unroll
  for (int j = 0; j < 16; ++j) {
    int i = j * 256 + t;
    int arr = i >> 11, rem = i & 2047, r = rem >> 7, e = rem & 127;
    const float* src = arr ? text : cond;
    float v = src[(size_t)(b0 + r) * 128 + e];
    short h, l;
    split2(v, h, l);
    int row = (4 + arr) * 16 + r;
    int si = row * 128 + (e ^ ((row & 7) << 3));
    lds_hi[si] = h; lds_lo[si] = l;
  }
  {
    f32x4 acc[8];
    #pragma unroll
    for (int n8 = 0; n8 < 8; ++n8) acc[n8] = (f32x4){0.f, 0.f, 0.f, 0.f};
    float4 avB[8];
    #pragma unroll
    for (int ks = 0; ks < 4; ++ks) {
      avB[2 * ks]     = *(const float4*)(arow + (4 + ks) * 32);
      avB[2 * ks + 1] = *(const float4*)(arow + (4 + ks) * 32 + 4);
    }
    #pragma unroll
    for (int ks = 0; ks < 8; ++ks) {
      bf16x8 ah, al;
      {
        float4 v0 = (ks < 4) ? avA[2 * ks] : avB[2 * (ks - 4)];
        float4 v1 = (ks < 4) ? avA[2 * ks + 1] : avB[2 * (ks - 4) + 1];
        #pragma unroll
        for (int j = 0; j < 4; ++j) {
          short h, l;
          split2(v0[j], h, l);
          ah[j] = h; al[j] = l;
          split2(v1[j], h, l);
          ah[4 + j] = h; al[4 + j] = l;
        }
      }
      #pragma unroll
      for (int n8 = 0; n8 < 8; ++n8) {
        bf16x8 bh = nwh[(n8 * 8 + ks) * 64 + lane];
        bf16x8 bl = nwl[(n8 * 8 + ks) * 64 + lane];
        acc[n8] = MFMA16(ah, bh, acc[n8], 0, 0, 0);
        acc[n8] = MFMA16(al, bh, acc[n8], 0, 0, 0);
        acc[n8] = MFMA16(ah, bl, acc[n8], 0, 0, 0);
      }
    }
    float ev[32];
    #pragma unroll
    for (int n8 = 0; n8 < 8; ++n8)
      #pragma unroll
      for (int rg = 0; rg < 4; ++rg)
        ev[n8 * 4 + rg] = ent[(size_t)eid[rg] * 128 + n8 * 16 + r15];
    #pragma unroll
    for (int n8 = 0; n8 < 8; ++n8) {
      int col = n8 * 16 + r15;
      float nb = node_b[col];
      #pragma unroll
      for (int rg = 0; rg < 4; ++rg) {
        float v = ev[n8 * 4 + rg] + fmaxf(acc[n8][rg] + nb, 0.f);
        short h, l; split2(v, h, l);
        int row = wv * 16 + q * 4 + rg;
        int si = row * 128 + (col ^ ((row & 7) << 3));
        lds_hi[si] = h; lds_lo[si] = l;
      }
    }
  }
  __syncthreads();
  {
    f32x4 xacc[6][2];
    #pragma unroll
    for (int a = 0; a < 6; ++a) {
      xacc[a][0] = (f32x4){0.f, 0.f, 0.f, 0.f};
      xacc[a][1] = (f32x4){0.f, 0.f, 0.f, 0.f};
    }
    #pragma unroll
    for (int ks = 0; ks < 4; ++ks) {
      int k0 = ks * 32 + q * 8;
      #pragma unroll
      for (int ha = 0; ha < 2; ++ha) {
        bf16x8 ah[3], al[3];
        #pragma unroll
        for (int j = 0; j < 3; ++j) {
          int row = (ha * 3 + j) * 16 + r15;
          int si = row * 128 + (k0 ^ ((row & 7) << 3));
          ah[j] = *(const bf16x8*)&lds_hi[si];
          al[j] = *(const bf16x8*)&lds_lo[si];
        }
        #pragma unroll
        for (int jn = 0; jn < 2; ++jn) {
          bf16x8 bh = wch[((wv * 2 + jn) * 4 + ks) * 64 + lane];
          bf16x8 bl = wcl[((wv * 2 + jn) * 4 + ks) * 64 + lane];
          #pragma unroll
          for (int j = 0; j < 3; ++j) {
            int a = ha * 3 + j;
            xacc[a][jn] = MFMA16(ah[j], bh, xacc[a][jn], 0, 0, 0);
            xacc[a][jn] = MFMA16(al[j], bh, xacc[a][jn], 0, 0, 0);
            xacc[a][jn] = MFMA16(ah[j], bl, xacc[a][jn], 0, 0, 0);
          }
        }
      }
    }
    __syncthreads();
    #pragma unroll
    for (int a = 0; a < 6; ++a) {
      #pragma unroll
      for (int jn = 0; jn < 2; ++jn) {
        int col = (wv * 2 + jn) * 16 + r15;
        float bv = bias_af[a * 128 + col];
        #pragma unroll
        for (int rg = 0; rg < 4; ++rg) {
          float v = fmaxf(xacc[a][jn][rg] + bv, 0.f);
          short h, l; split2(v, h, l);
          int row = a * 16 + q * 4 + rg;
          int si = row * 128 + (col ^ ((row & 7) << 3));
          lds_hi[si] = h; lds_lo[si] = l;
        }
      }
    }
  }
  __syncthreads();
  f32x4 mreg[8];
  #pragma unroll
  for (int grp = 0; grp < 4; ++grp) {
    f32x4 acc[6][2];
    #pragma unroll
    for (int a = 0; a < 6; ++a) {
      acc[a][0] = (f32x4){0.f, 0.f, 0.f, 0.f};
      acc[a][1] = (f32x4){0.f, 0.f, 0.f, 0.f};
    }
    #pragma unroll
    for (int ks = 0; ks < 4; ++ks) {
      int k0 = ks * 32 + q * 8;
      #pragma unroll
      for (int ha = 0; ha < 2; ++ha) {
        bf16x8 ah[3], al[3];
        #pragma unroll
        for (int j = 0; j < 3; ++j) {
          int row = (ha * 3 + j) * 16 + r15;
          int si = row * 128 + (k0 ^ ((row & 7) << 3));
          ah[j] = *(const bf16x8*)&lds_hi[si];
          al[j] = *(const bf16x8*)&lds_lo[si];
        }
        #pragma unroll
        for (int jn = 0; jn < 2; ++jn) {
          int nfg = wv * 8 + grp * 2 + jn;
          bf16x8 bh = gfh[(nfg * 4 + ks) * 64 + lane];
          bf16x8 bl = gfl[(nfg * 4 + ks) * 64 + lane];
          #pragma unroll
          for (int j = 0; j < 3; ++j) {
            int a = ha * 3 + j;
            acc[a][jn] = MFMA16(ah[j], bh, acc[a][jn], 0, 0, 0);
            acc[a][jn] = MFMA16(al[j], bh, acc[a][jn], 0, 0, 0);
            acc[a][jn] = MFMA16(ah[j], bl, acc[a][jn], 0, 0, 0);
          }
        }
      }
    }
    #pragma unroll
    for (int jn = 0; jn < 2; ++jn) {
      #pragma unroll
      for (int rg = 0; rg < 4; ++rg) {
        float mm = acc[0][jn][rg];
        #pragma unroll
        for (int a = 1; a < 6; ++a) mm = fminf(mm, acc[a][jn][rg]);
        mreg[grp * 2 + jn][rg] = mm;
      }
    }
  }
  __syncthreads();
  {
    float* dst = (wv >= 2) ? vmin_s : umin_s;
    int cbase = (wv & 1) * 128;
    #pragma unroll
    for (int j = 0; j < 8; ++j) {
      int colg = cbase + j * 16 + r15;
      #pragma unroll
      for (int rg = 0; rg < 4; ++rg)
        dst[(q * 4 + rg) * OV + colg] = mreg[j][rg];
    }
  }
  __syncthreads();
  #pragma unroll
  for (int j = 0; j < 16; ++j) {
    int i = j * 256 + t;
    int r = i >> 8, g = i & 255;
    out[(size_t)(b0 + r) * 256 + g] =
        fmaxf(umin_s[r * OV + g] + vmin_s[r * OV + g] + gfcn_b[g], 0.f);
  }
}

extern "C" void kernel_launch(void* const* d_in, const int* in_sizes, int n_in,
                              void* d_out, int out_size, void* d_ws, size_t ws_size,
                              hipStream_t stream) {
  const int* a_ids = (const int*)d_in[0];
  const int* b_ids = (const int*)d_in[1];
  const int* c_ids = (const int*)d_in[2];
  const int* event_ids = (const int*)d_in[3];
  const float* node_features = (const float*)d_in[4];
  const float* cond_rel = (const float*)d_in[5];
  const float* text = (const float*)d_in[6];
  const float* entity_emb = (const float*)d_in[7];
  const float* role_emb = (const float*)d_in[8];
  const float* node_W = (const float*)d_in[9];
  const float* node_b = (const float*)d_in[10];
  const float* conv_W = (const float*)d_in[11];
  const float* conv_b = (const float*)d_in[12];
  const float* bn_gamma = (const float*)d_in[13];
  const float* bn_beta = (const float*)d_in[14];
  const float* bn_mean = (const float*)d_in[15];
  const float* bn_var = (const float*)d_in[16];
  const float* gfcn_W = (const float*)d_in[17];
  const float* gfcn_b = (const float*)d_in[18];
  float* out = (float*)d_out;

  short* wsS = (short*)d_ws;
  float* bias_af = (float*)((char*)d_ws + OFF_BIAS_BYTES);
  const int B = in_sizes[0];   // 32768
  const int NT = B / 16;       // 2048

  setup_kernel<<<452, 256, 0, stream>>>(node_W, conv_W, gfcn_W, role_emb,
                                        conv_b, bn_gamma, bn_beta, bn_mean,
                                        bn_var, wsS, bias_af);
  if (ws_size >= WS_NEED && NT <= NT_MAX) {
    short* vfh = (short*)((char*)d_ws + OFF_VF_BYTES);
    short* vfl = vfh + VF_SH;
    ent_kernel<<<NT, 256, 0, stream>>>(a_ids, b_ids, c_ids, event_ids,
                                       node_features, entity_emb, node_b,
                                       wsS, vfh, vfl);
    head_kernel<<<NT, 256, 0, stream>>>(cond_rel, text, gfcn_b, wsS, bias_af,
                                        vfh, vfl, out);
  } else {
    fused_fallback<<<NT, 256, 0, stream>>>(
        a_ids, b_ids, c_ids, event_ids, node_features, cond_rel, text,
        entity_emb, node_b, gfcn_b, wsS, bias_af, out);
  }
}